// Round 1
// baseline (184.762 us; speedup 1.0000x reference)
//
#include <hip/hip_runtime.h>

// ---------------------------------------------------------------------------
// ContrastiveLoss: loss = mean_i [ 0.5*(LSE_row_i + LSE_col_i) - diag_i ]
// over logits = normalize(img) @ normalize(txt)^T / 0.07, N=8192, D=1024.
// |logit| <= 14.29 -> exp() safe in fp32, no max subtraction needed.
//
// R15 = structural jump: 256x256 tile, 8 waves (2x4, 128x64/wave),
// double-buffered LDS (128 KB, 1 block/CU) + counted s_waitcnt vmcnt(8)
// + raw s_barrier (T3+T4) + setprio around per-phase MFMA clusters (T5).
// Rationale: R14's 2-barrier single-buffer structure is at the known ~30%
// MfmaUtil regime ceiling; 256^2 cuts LDS traffic/FLOP 22.9->15.2 mB/FLOP
// and dbuf+counted-vmcnt keeps one full K-step of staging in flight
// (never drained to 0 in the main loop).
// Carried: R7/R10 producer-side even/odd chunk interleave -> zero-conflict
// b128 LDS reads (slot = quad ^ ((row>>1)&3), row-local so it scales to 256
// rows unchanged); R13 inverted XCD swizzle (adapted to 32x32 block grid);
// R4 - only b128 is conflict-free under 16B swizzle; R1 - staging lane->addr
// segment-monotone per quarter-wave. New: aoff/boff slot-xor is
// tm-independent ((Ra>>1)&3 == (lanelo>>1)&3) -> single base + tm*1024
// immediate offsets.
// vmcnt ledger (8 gloads/wave/stage): prologue stages k=0,1 (16 out);
// step k: vmcnt(8) retires stage(k) exactly, stage(k+1) stays in flight;
// bar; reads (consumed by MFMA pre-bar2 -> lgkm drained); bar;
// stage(k+2) overwrites just-read buffer. Last step vmcnt(0).
// ---------------------------------------------------------------------------

#define BM 256
#define BN 256
#define BKB 128   // fp8 K-bytes per iteration (one MFMA k-step)

typedef float floatx4 __attribute__((ext_vector_type(4)));
typedef int   intx4   __attribute__((ext_vector_type(4)));
typedef int   intx8   __attribute__((ext_vector_type(8)));

__device__ __forceinline__ void gload_lds16(const unsigned char* g, unsigned char* lds) {
    __builtin_amdgcn_global_load_lds(
        (const __attribute__((address_space(1))) void*)g,
        (__attribute__((address_space(3))) void*)lds,
        16, 0, 0);
}

// ---- Kernel 1: row L2-normalize, x16, fp32 -> fp8 e4m3, chunk-interleaved --
// One wave per row, 4 rows/block. Rows [0,N)->img, [N,2N)->txt.
// Output dword d of a 256-dword row stored at d' = (d&~31)|(p*4+(d&3)),
// chunk c = (d>>2)&7, p = (c&1)*4 + (c>>1) (even chunks -> first 64B half).
// Side duty: zero rowsum/colsum (2N floats) and out.
__global__ __launch_bounds__(256)
void normalize_fp8(const float* __restrict__ img, const float* __restrict__ txt,
                   unsigned int* __restrict__ oimg, unsigned int* __restrict__ otxt,
                   float* __restrict__ sums, float* __restrict__ out, int N) {
    const int gi = blockIdx.x * 256 + threadIdx.x;
    if (gi < 2 * N) sums[gi] = 0.f;
    if (gi == 0) out[0] = 0.f;

    const int gw = blockIdx.x * 4 + (threadIdx.x >> 6);   // row id in [0,2N)
    const int lane = threadIdx.x & 63;
    const float* in = (gw < N) ? img : txt;
    unsigned int* o = (gw < N) ? oimg : otxt;
    const int row = (gw < N) ? gw : gw - N;
    const float4* rp = (const float4*)(in + (size_t)row * 1024);

    float4 v[4];
    float ss = 0.f;
    #pragma unroll
    for (int j = 0; j < 4; ++j) {
        v[j] = rp[j * 64 + lane];
        ss += v[j].x * v[j].x + v[j].y * v[j].y + v[j].z * v[j].z + v[j].w * v[j].w;
    }
    #pragma unroll
    for (int o2 = 1; o2 < 64; o2 <<= 1) ss += __shfl_xor(ss, o2);
    const float inv = 16.0f / fmaxf(sqrtf(ss), 1e-8f);   // x16 quantization scale
    #pragma unroll
    for (int j = 0; j < 4; ++j) {
        int p = __builtin_amdgcn_cvt_pk_fp8_f32(v[j].x * inv, v[j].y * inv, 0, false);
        p = __builtin_amdgcn_cvt_pk_fp8_f32(v[j].z * inv, v[j].w * inv, p, true);
        const int d = j * 64 + lane;
        const int c = (d >> 2) & 7;
        const int pp = (c & 1) * 4 + (c >> 1);
        const int dp = (d & ~31) | (pp * 4 + (d & 3));
        o[(size_t)row * 256 + dp] = (unsigned int)p;
    }
}

// ---- Kernel 2: 256x256-tile NT MX-fp8 GEMM + fused exp/row-col sums/diag ---
__global__ __launch_bounds__(512, 2)
void gemm_exp_kernel(const unsigned char* __restrict__ A,   // img_q [N][K] fp8 (interleaved)
                     const unsigned char* __restrict__ B,   // txt_q [N][K] fp8 (interleaved)
                     float* __restrict__ rowsum, float* __restrict__ colsum,
                     float* __restrict__ diag, int K, float scale) {
    // XCD-inverted swizzle for 32x32 block grid: xcd = id&7 owns bm strip
    // [xcd*4, xcd*4+4) x all bn; bijective for 1024 = 8*4*32 blocks.
    const int id = blockIdx.x;
    const int idp = id >> 3;
    const int bm = (id & 7) * 4 + (idp & 3);
    const int bn = idp >> 2;

    // LDS: per matrix, 2 buffers x 2 windows x [256 rows][64B] = 64 KB.
    // slot s of row r (within a 64B window) holds global chunk s ^ ((r>>1)&3);
    // window0 = even k-chunks, window1 (+16384) = odd (producer interleave).
    __shared__ unsigned char As[2 * 2 * 256 * 64];   // 64 KB
    __shared__ unsigned char Bs[2 * 2 * 256 * 64];   // 64 KB

    const int tid = threadIdx.x;
    const int lane = tid & 63;
    const int wave = tid >> 6;           // 0..7
    const int quad = lane >> 4;
    const int lanelo = lane & 15;
    const int wr = wave >> 2;            // 0..1  (row strip of 128)
    const int wc = wave & 3;             // 0..3  (col strip of 64)
    const int wrow = wr * 128;
    const int wcol = wc * 64;

    floatx4 acc[8][4] = {};

    // Staging: unit c in [0,1024) per matrix covers (row c>>2, slot c&3);
    // 512 threads x 2 units; global chunk fetched = slot ^ swz(row).
    const int c0 = tid;
    const int c1 = tid + 512;
    const int r0 = c0 >> 2, r1 = c1 >> 2;
    const int kg0 = ((c0 & 3) ^ ((r0 >> 1) & 3)) * 16;
    const int kg1 = ((c1 & 3) ^ ((r1 >> 1) & 3)) * 16;

    const unsigned char* pa0 = A + ((size_t)bm * BM + r0) * K + kg0;
    const unsigned char* pa1 = A + ((size_t)bm * BM + r1) * K + kg1;
    const unsigned char* pb0 = B + ((size_t)bn * BN + r0) * K + kg0;
    const unsigned char* pb1 = B + ((size_t)bn * BN + r1) * K + kg1;

    // Fragment LDS offsets: slot-xor is tm-independent since
    // ((wrow + tm*16 + lanelo)>>1)&3 == (lanelo>>1)&3 (wrow,16*tm = 0 mod 8).
    const int swx = (quad ^ ((lanelo >> 1) & 3)) * 16;
    const int aoffB = (wrow + lanelo) * 64 + swx;
    const int boffB = (wcol + lanelo) * 64 + swx;

    auto stage = [&](int k, int buf) {
        unsigned char* dA = As + buf * 32768 + c0 * 16;   // c1*16 = c0*16 + 8192
        unsigned char* dB = Bs + buf * 32768 + c0 * 16;
        #pragma unroll
        for (int w = 0; w < 2; ++w) {
            gload_lds16(pa0 + k + w * 64, dA + w * 16384);
            gload_lds16(pa1 + k + w * 64, dA + 8192 + w * 16384);
            gload_lds16(pb0 + k + w * 64, dB + w * 16384);
            gload_lds16(pb1 + k + w * 64, dB + 8192 + w * 16384);
        }
    };

    stage(0, 0);
    stage(BKB, 1);
    for (int k = 0, it = 0; k < K; k += BKB, ++it) {
        const int buf = it & 1;
        // Counted wait: retire exactly stage(k); keep stage(k+1) in flight.
        if (k + BKB < K) { asm volatile("s_waitcnt vmcnt(8)" ::: "memory"); }
        else             { asm volatile("s_waitcnt vmcnt(0)" ::: "memory"); }
        __builtin_amdgcn_s_barrier();

        const unsigned char* Ab = As + buf * 32768;
        const unsigned char* Bb = Bs + buf * 32768;

        intx8 bg[4];
        #pragma unroll
        for (int t = 0; t < 4; ++t) {
            const intx4 blo = *(const intx4*)(Bb + boffB + t * 1024);
            const intx4 bhi = *(const intx4*)(Bb + 16384 + boffB + t * 1024);
            bg[t] = __builtin_shufflevector(blo, bhi, 0, 1, 2, 3, 4, 5, 6, 7);
        }

        #pragma unroll
        for (int ph = 0; ph < 4; ++ph) {
            intx8 af[2];
            #pragma unroll
            for (int t = 0; t < 2; ++t) {
                const int tm = ph * 2 + t;
                const intx4 alo = *(const intx4*)(Ab + aoffB + tm * 1024);
                const intx4 ahi = *(const intx4*)(Ab + 16384 + aoffB + tm * 1024);
                af[t] = __builtin_shufflevector(alo, ahi, 0, 1, 2, 3, 4, 5, 6, 7);
            }
            __builtin_amdgcn_s_setprio(1);
            #pragma unroll
            for (int t = 0; t < 2; ++t)
                #pragma unroll
                for (int tn = 0; tn < 4; ++tn)
                    acc[ph * 2 + t][tn] = __builtin_amdgcn_mfma_scale_f32_16x16x128_f8f6f4(
                        af[t], bg[tn], acc[ph * 2 + t][tn],
                        0, 0,          // cbsz = fp8 e4m3, blgp = fp8 e4m3
                        0, 127,        // A scale: 1.0
                        0, 127);       // B scale: 1.0
            __builtin_amdgcn_s_setprio(0);
        }

        __builtin_amdgcn_s_barrier();            // all waves' reads consumed
        if (k + 2 * BKB < K) stage(k + 2 * BKB, buf);   // overwrite freed buffer
    }

    // ---- epilogue: scale, capture diag, exp in place ----
    const int growb = bm * BM + wrow;
    const int gcolb = bn * BN + wcol;

    #pragma unroll
    for (int tm = 0; tm < 8; ++tm)
        #pragma unroll
        for (int tn = 0; tn < 4; ++tn)
            #pragma unroll
            for (int r = 0; r < 4; ++r) {
                const float l = acc[tm][tn][r] * scale;
                const int grow = growb + tm * 16 + quad * 4 + r;
                const int gcol = gcolb + tn * 16 + lanelo;
                if (grow == gcol) diag[grow] = l;
                acc[tm][tn][r] = __expf(l);
            }

    // ---- row sums: reduce over the 16 lanes sharing a row, then atomicAdd ----
    #pragma unroll
    for (int tm = 0; tm < 8; ++tm) {
        floatx4 rs = acc[tm][0] + acc[tm][1] + acc[tm][2] + acc[tm][3];
        #pragma unroll
        for (int r = 0; r < 4; ++r) {
            float v = rs[r];
            v += __shfl_xor(v, 1);
            v += __shfl_xor(v, 2);
            v += __shfl_xor(v, 4);
            v += __shfl_xor(v, 8);
            if (lanelo == 0)
                atomicAdd(&rowsum[growb + tm * 16 + quad * 4 + r], v);
        }
    }

    // ---- col sums: reduce over quads (xor 16, 32), then atomicAdd ----
    #pragma unroll
    for (int tn = 0; tn < 4; ++tn) {
        float cs = 0.f;
        #pragma unroll
        for (int tm = 0; tm < 8; ++tm)
            cs += acc[tm][tn][0] + acc[tm][tn][1] + acc[tm][tn][2] + acc[tm][tn][3];
        cs += __shfl_xor(cs, 16);
        cs += __shfl_xor(cs, 32);
        if (quad == 0)
            atomicAdd(&colsum[gcolb + tn * 16 + lanelo], cs);
    }
}

// ---- Kernel 3: loss = mean( 0.5*(log(rowsum)+log(colsum)) - diag ) ---------
// out zeroed by normalize_fp8 (stream-ordered before this kernel).
__global__ __launch_bounds__(256)
void final_reduce(const float* __restrict__ rowsum, const float* __restrict__ colsum,
                  const float* __restrict__ diag, float* __restrict__ out, int n) {
    const int i = blockIdx.x * 256 + threadIdx.x;
    const int t = threadIdx.x;
    float v = 0.5f * (logf(rowsum[i]) + logf(colsum[i])) - diag[i];
    #pragma unroll
    for (int o = 1; o < 64; o <<= 1) v += __shfl_xor(v, o);
    __shared__ float ws[4];
    if ((t & 63) == 0) ws[t >> 6] = v;
    __syncthreads();
    if (t == 0) atomicAdd(out, (ws[0] + ws[1] + ws[2] + ws[3]) / (float)n);
}

extern "C" void kernel_launch(void* const* d_in, const int* in_sizes, int n_in,
                              void* d_out, int out_size, void* d_ws, size_t ws_size,
                              hipStream_t stream) {
    const float* img = (const float*)d_in[0];
    const float* txt = (const float*)d_in[1];
    float* out = (float*)d_out;

    const int D = 1024;
    const int N = in_sizes[0] / D;   // 8192

    unsigned char* imgq = (unsigned char*)d_ws;
    unsigned char* txtq = imgq + (size_t)N * D;
    float* rowsum = (float*)(txtq + (size_t)N * D);   // rowsum[N] ++ colsum[N]
    float* colsum = rowsum + N;
    float* diag = colsum + N;

    normalize_fp8<<<2 * N / 4, 256, 0, stream>>>(img, txt, (unsigned int*)imgq,
                                                 (unsigned int*)txtq, rowsum, out, N);

    // acc = sum of (16a)(16b) = 256*cos; scale undoes 256 and applies 1/T.
    gemm_exp_kernel<<<(N / BM) * (N / BN), 512, 0, stream>>>(
        imgq, txtq, rowsum, colsum, diag, D, 1.0f / (256.0f * 0.07f));
    final_reduce<<<N / 256, 256, 0, stream>>>(rowsum, colsum, diag, out, N);
}